// Round 11
// baseline (699.221 us; speedup 1.0000x reference)
//
#include <hip/hip_runtime.h>
#include <math.h>

#define SEQ 2048
#define DMODEL 1024
#define NHEADS 16
#define DHEAD 64

// lmin sharding: 64 slices per head, each slice on its own 128B line
#define LSLOTS 64
#define LSTRIDE 32   // uints between slots (128 bytes)

typedef long long i64;
typedef unsigned short u16;
typedef __attribute__((ext_vector_type(4))) float f32x4;
typedef __attribute__((ext_vector_type(8))) short bf16x8;

#define IN_E  2097152   // 2048*1024
#define W_E   1048576   // 1024*1024
#define HEAD_E 131072   // 2048*64

__device__ inline u16 f2bf(float x) {                // RNE
    union { float f; unsigned u; } v; v.f = x;
    unsigned r = v.u + 0x7FFF + ((v.u >> 16) & 1);
    return (u16)(r >> 16);
}
__device__ inline float bf2f(u16 h) {
    union { unsigned u; float f; } v; v.u = ((unsigned)h) << 16;
    return v.f;
}

__device__ inline void gload16(const void* g, void* l) {
    __builtin_amdgcn_global_load_lds(
        (const __attribute__((address_space(1))) unsigned int*)g,
        (__attribute__((address_space(3))) unsigned int*)l, 16, 0, 0);
}

struct SplitArgs {
    const float* src[8];
    u16* dh[8];
    u16* dl[8];
    int n4[8];
};
__global__ __launch_bounds__(256)
void split_all(SplitArgs a)
{
    const int z = blockIdx.y;
    const int i = blockIdx.x * 256 + threadIdx.x;
    if (i >= a.n4[z]) return;
    const float4 x = ((const float4*)a.src[z])[i];
    u16 h0 = f2bf(x.x), h1 = f2bf(x.y), h2 = f2bf(x.z), h3 = f2bf(x.w);
    u16 l0 = f2bf(x.x - bf2f(h0)), l1 = f2bf(x.y - bf2f(h1));
    u16 l2 = f2bf(x.z - bf2f(h2)), l3 = f2bf(x.w - bf2f(h3));
    uint2 hh; hh.x = (unsigned)h0 | ((unsigned)h1 << 16); hh.y = (unsigned)h2 | ((unsigned)h3 << 16);
    uint2 ll; ll.x = (unsigned)l0 | ((unsigned)l1 << 16); ll.y = (unsigned)l2 | ((unsigned)l3 << 16);
    ((uint2*)a.dh[z])[i] = hh;
    ((uint2*)a.dl[z])[i] = ll;
}

__global__ __launch_bounds__(256)
void posenc_split(u16* __restrict__ dh, u16* __restrict__ dl)
{
    const int idx = blockIdx.x * 256 + threadIdx.x;
    const int f = idx >> 10;
    const int i = idx & 1023;
    const float P = (float)(SEQ - 1 - f);
    const float ex = (float)(i & ~1) * (1.f / 1024.f);
    const float dv = __expf(ex * -9.210340372f);   // 10000^-ex
    const float ang = P * dv;
    const float val = (i & 1) ? __cosf(ang) : __sinf(ang);
    const u16 hb = f2bf(val);
    dh[idx] = hb;
    dl[idx] = f2bf(val - bf2f(hb));
}

struct TNArgs {
    const u16 *Ah, *Al, *Bh, *Bl;
    i64 sAz, sBz;
    float* Cf; i64 sCz; int ldc;
    u16 *O1h, *O1l, *O2h, *O2l;
    const float *b1, *b2;
    int K, mode;
};

__global__ __launch_bounds__(256)
void mfma_tn128(TNArgs p)
{
    __shared__ __align__(16) u16 Ash[128 * 32];
    __shared__ __align__(16) u16 Asl[128 * 32];
    __shared__ __align__(16) u16 Bsh[128 * 32];
    __shared__ __align__(16) u16 Bsl[128 * 32];
    const int tid = threadIdx.x, wave = tid >> 6, lane = tid & 63;
    const int z = blockIdx.z;
    const i64 m0 = (i64)blockIdx.y * 128, n0 = (i64)blockIdx.x * 128;
    const int K = p.K;
    const u16* Abh = p.Ah + (i64)z * p.sAz;
    const u16* Abl = p.Al + (i64)z * p.sAz;
    const u16* Bbh = p.Bh + (i64)z * p.sBz;
    const u16* Bbl = p.Bl + (i64)z * p.sBz;
    const int r0 = tid >> 2, kc = (tid & 3) * 8;
    const int r1 = r0 + 64;
    u16* dA0 = &Ash[wave * 512];
    u16* dA1 = &Ash[2048 + wave * 512];
    u16* dA0l = &Asl[wave * 512];
    u16* dA1l = &Asl[2048 + wave * 512];
    u16* dB0 = &Bsh[wave * 512];
    u16* dB1 = &Bsh[2048 + wave * 512];
    u16* dB0l = &Bsl[wave * 512];
    u16* dB1l = &Bsl[2048 + wave * 512];
    const int wm = (wave >> 1) * 64, wn = (wave & 1) * 64;
    f32x4 acc[4][4] = {};

    for (int k0 = 0; k0 < K; k0 += 32) {
        __syncthreads();
        const i64 ga0 = (m0 + r0) * K + k0 + kc;
        const i64 ga1 = (m0 + r1) * K + k0 + kc;
        const i64 gb0 = (n0 + r0) * K + k0 + kc;
        const i64 gb1 = (n0 + r1) * K + k0 + kc;
        gload16(Abh + ga0, dA0);  gload16(Abh + ga1, dA1);
        gload16(Abl + ga0, dA0l); gload16(Abl + ga1, dA1l);
        gload16(Bbh + gb0, dB0);  gload16(Bbh + gb1, dB1);
        gload16(Bbl + gb0, dB0l); gload16(Bbl + gb1, dB1l);
        __syncthreads();
        const int fr = lane & 15, fk = (lane >> 4) * 8;
        bf16x8 fah[4], fal[4], fbh[4], fbl[4];
#pragma unroll
        for (int t = 0; t < 4; ++t) {
            fah[t] = *(const bf16x8*)&Ash[(wm + t * 16 + fr) * 32 + fk];
            fal[t] = *(const bf16x8*)&Asl[(wm + t * 16 + fr) * 32 + fk];
            fbh[t] = *(const bf16x8*)&Bsh[(wn + t * 16 + fr) * 32 + fk];
            fbl[t] = *(const bf16x8*)&Bsl[(wn + t * 16 + fr) * 32 + fk];
        }
#pragma unroll
        for (int mi = 0; mi < 4; ++mi)
#pragma unroll
            for (int ni = 0; ni < 4; ++ni) {
                acc[mi][ni] = __builtin_amdgcn_mfma_f32_16x16x32_bf16(fah[mi], fbh[ni], acc[mi][ni], 0, 0, 0);
                acc[mi][ni] = __builtin_amdgcn_mfma_f32_16x16x32_bf16(fah[mi], fbl[ni], acc[mi][ni], 0, 0, 0);
                acc[mi][ni] = __builtin_amdgcn_mfma_f32_16x16x32_bf16(fal[mi], fbh[ni], acc[mi][ni], 0, 0, 0);
            }
    }

    const int fr = lane & 15, fq = (lane >> 4) * 4;
    if (p.mode == 0) {
        float* C = p.Cf + (i64)z * p.sCz;
#pragma unroll
        for (int mi = 0; mi < 4; ++mi)
#pragma unroll
            for (int e = 0; e < 4; ++e) {
                const i64 row = m0 + wm + mi * 16 + fq + e;
#pragma unroll
                for (int ni = 0; ni < 4; ++ni)
                    C[row * p.ldc + n0 + wn + ni * 16 + fr] = acc[mi][ni][e];
            }
    } else if (p.mode == 1) {
        const i64 obase = (i64)z * IN_E;
#pragma unroll
        for (int mi = 0; mi < 4; ++mi)
#pragma unroll
            for (int e = 0; e < 4; ++e) {
                const i64 m = m0 + wm + mi * 16 + fq + e;
#pragma unroll
                for (int ni = 0; ni < 4; ++ni) {
                    const int c = (int)n0 + wn + ni * 16 + fr;
                    const int h = c >> 6, d = c & 63;
                    const i64 off = ((i64)h * SEQ + m) * DHEAD + d;
                    float v = acc[mi][ni][e];
                    if (z == 0) v += p.b1[c];
                    const u16 hb = f2bf(v);
                    const u16 lb = f2bf(v - bf2f(hb));
                    p.O1h[obase + off] = hb;
                    p.O1l[obase + off] = lb;
                    if (z == 0) {
                        const float v2 = acc[mi][ni][e] + p.b2[c];
                        const u16 hb2 = f2bf(v2);
                        const u16 lb2 = f2bf(v2 - bf2f(hb2));
                        p.O2h[off] = hb2;
                        p.O2l[off] = lb2;
                    }
                }
            }
    } else { // mode 2: exact GELU
        float* C = p.Cf;
#pragma unroll
        for (int mi = 0; mi < 4; ++mi)
#pragma unroll
            for (int e = 0; e < 4; ++e) {
                const i64 row = m0 + wm + mi * 16 + fq + e;
#pragma unroll
                for (int ni = 0; ni < 4; ++ni) {
                    const float x = acc[mi][ni][e];
                    C[row * p.ldc + n0 + wn + ni * 16 + fr] =
                        0.5f * x * (1.f + erff(x * 0.70710678118654752f));
                }
            }
    }
}

// ---------------------------------------------------------------------------
// PV: O[m, (h0+z)*64+d] = sum_f W[h0+z][m][f] * V[h0+z][f][d]
// 64-row strips, full CU coverage. Called per-chunk so the W slice written by
// the immediately-preceding softmax is still L3-resident (chunk*16MB + G +
// vvT + mask < 256MB L3) -> A-reads are L3 hits instead of HBM.
// Wgt/VTh/VTl passed pre-offset to h0; h0 only shifts the output column.
// ---------------------------------------------------------------------------
__global__ __launch_bounds__(256)
void mfma_pv(const float* __restrict__ Wgt, const u16* __restrict__ VTh,
             const u16* __restrict__ VTl, u16* __restrict__ Oh, u16* __restrict__ Ol,
             int h0)
{
    __shared__ __align__(16) float Asf[64 * 32];
    __shared__ __align__(16) u16 Bsh[64 * 32];
    __shared__ __align__(16) u16 Bsl[64 * 32];
    const int tid = threadIdx.x, wave = tid >> 6, lane = tid & 63;
    const int z = blockIdx.z;
    const i64 m0 = (i64)blockIdx.y * 64;
    const float* A = Wgt + (i64)z * SEQ * SEQ;
    const u16* Bh = VTh + (i64)z * HEAD_E;
    const u16* Bl = VTl + (i64)z * HEAD_E;
    const int ar = tid >> 3, akc = (tid & 7) * 4;
    const int br = tid >> 2, bkc = (tid & 3) * 8;
    const int wm = wave * 16;
    f32x4 acc[4] = {};

    for (int k0 = 0; k0 < SEQ; k0 += 32) {
        __syncthreads();
#pragma unroll
        for (int i = 0; i < 2; ++i)
            gload16(A + (m0 + ar + i * 32) * SEQ + k0 + akc, &Asf[(i * 256 + wave * 64) * 4]);
        gload16(Bh + (i64)br * SEQ + k0 + bkc, &Bsh[wave * 512]);
        gload16(Bl + (i64)br * SEQ + k0 + bkc, &Bsl[wave * 512]);
        __syncthreads();
        const int fr = lane & 15, fk = (lane >> 4) * 8;
        bf16x8 fbh[4], fbl[4];
#pragma unroll
        for (int t = 0; t < 4; ++t) {
            fbh[t] = *(const bf16x8*)&Bsh[(t * 16 + fr) * 32 + fk];
            fbl[t] = *(const bf16x8*)&Bsl[(t * 16 + fr) * 32 + fk];
        }
        const float4 x0 = *(const float4*)&Asf[(wm + fr) * 32 + fk];
        const float4 x1 = *(const float4*)&Asf[(wm + fr) * 32 + fk + 4];
        float av[8] = { x0.x, x0.y, x0.z, x0.w, x1.x, x1.y, x1.z, x1.w };
        bf16x8 ah, al;
#pragma unroll
        for (int j = 0; j < 8; ++j) {
            union { float f; unsigned u; } v; v.f = av[j];
            const u16 hb = (u16)(v.u >> 16);
            union { unsigned u; float f; } fh; fh.u = v.u & 0xFFFF0000u;
            union { float f; unsigned u; } rm; rm.f = av[j] - fh.f;
            ah[j] = (short)hb;
            al[j] = (short)(u16)(rm.u >> 16);
        }
#pragma unroll
        for (int ni = 0; ni < 4; ++ni) {
            acc[ni] = __builtin_amdgcn_mfma_f32_16x16x32_bf16(ah, fbh[ni], acc[ni], 0, 0, 0);
            acc[ni] = __builtin_amdgcn_mfma_f32_16x16x32_bf16(ah, fbl[ni], acc[ni], 0, 0, 0);
            acc[ni] = __builtin_amdgcn_mfma_f32_16x16x32_bf16(al, fbh[ni], acc[ni], 0, 0, 0);
        }
    }

    const int fr = lane & 15, fq = (lane >> 4) * 4;
#pragma unroll
    for (int e = 0; e < 4; ++e) {
        const i64 m = m0 + wm + fq + e;
#pragma unroll
        for (int ni = 0; ni < 4; ++ni) {
            const int c = (h0 + z) * 64 + ni * 16 + fr;
            const float v = acc[ni][e];
            const u16 hb = f2bf(v);
            Oh[m * DMODEL + c] = hb;
            Ol[m * DMODEL + c] = f2bf(v - bf2f(hb));
        }
    }
}

__global__ __launch_bounds__(256)
void transpose_vv(const u16* __restrict__ vh, const u16* __restrict__ vl,
                  u16* __restrict__ th, u16* __restrict__ tl)
{
    __shared__ u16 tile[64][65];
    const int tid = threadIdx.x;
    const int h = blockIdx.y, f0 = blockIdx.x * 64;
    const i64 src = ((i64)h * SEQ + f0) * DHEAD;
    const i64 dst = (i64)h * HEAD_E + f0;
#pragma unroll
    for (int i = 0; i < 16; ++i) {
        const int idx = i * 256 + tid;
        const int r = idx >> 6, c = idx & 63;
        tile[c][r] = vh[src + (i64)r * 64 + c];
    }
    __syncthreads();
#pragma unroll
    for (int i = 0; i < 16; ++i) {
        const int idx = i * 256 + tid;
        const int d = idx >> 6, fl = idx & 63;
        th[dst + (i64)d * SEQ + fl] = tile[d][fl];
    }
    __syncthreads();
#pragma unroll
    for (int i = 0; i < 16; ++i) {
        const int idx = i * 256 + tid;
        const int r = idx >> 6, c = idx & 63;
        tile[c][r] = vl[src + (i64)r * 64 + c];
    }
    __syncthreads();
#pragma unroll
    for (int i = 0; i < 16; ++i) {
        const int idx = i * 256 + tid;
        const int d = idx >> 6, fl = idx & 63;
        tl[dst + (i64)d * SEQ + fl] = tile[d][fl];
    }
}

__global__ __launch_bounds__(256)
void softmax_rows(float* __restrict__ Wbase, const float* __restrict__ Gbase,
                  const float* __restrict__ mask, unsigned int* __restrict__ lmin, int h0)
{
    __shared__ float red[4];
    const int hl = blockIdx.y;
    float* Wh = Wbase + (i64)(h0 + hl) * SEQ * SEQ;
    const float* G = Gbase + (i64)hl * SEQ * SEQ;
    const int i = blockIdx.x;
    const int tx = threadIdx.x;
    const i64 rowoff = (i64)i * SEQ;
    float s[8];
    float mloc = -3.0e38f;
#pragma unroll
    for (int r = 0; r < 8; ++r) {
        const int j = tx + (r << 8);
        float bd;
        if (j <= i)          bd = G[rowoff + (SEQ - 1 - i + j)];
        else if (j == i + 1) bd = 0.f;
        else                 bd = G[rowoff + SEQ + (j - i - 2)];
        const float v = (Wh[rowoff + j] + bd) * 0.03125f + mask[rowoff + j];
        s[r] = v;
        mloc = fmaxf(mloc, v);
    }
#pragma unroll
    for (int o = 32; o > 0; o >>= 1) mloc = fmaxf(mloc, __shfl_xor(mloc, o));
    if ((tx & 63) == 0) red[tx >> 6] = mloc;
    __syncthreads();
    const float m = fmaxf(fmaxf(red[0], red[1]), fmaxf(red[2], red[3]));
    __syncthreads();
    float lsum = 0.f;
#pragma unroll
    for (int r = 0; r < 8; ++r) { s[r] = __expf(s[r] - m); lsum += s[r]; }
#pragma unroll
    for (int o = 32; o > 0; o >>= 1) lsum += __shfl_xor(lsum, o);
    if ((tx & 63) == 0) red[tx >> 6] = lsum;
    __syncthreads();
    const float l = red[0] + red[1] + red[2] + red[3];
    const float inv = 1.f / l;
#pragma unroll
    for (int r = 0; r < 8; ++r) Wh[rowoff + tx + (r << 8)] = s[r] * inv;
    if (tx == 0)
        atomicMin(&lmin[(((h0 + hl) << 6) + (i & (LSLOTS - 1))) * LSTRIDE],
                  __float_as_uint(l));
}

__global__ __launch_bounds__(1024)
void init_kernel(unsigned int* __restrict__ lmin)
{
    lmin[threadIdx.x * LSTRIDE] = 0x7F7FFFFFu;
}

__global__ __launch_bounds__(1024)
void loss_kernel(const unsigned int* __restrict__ lmin, float* __restrict__ out)
{
    __shared__ float hs[16];
    const int w = threadIdx.x >> 6;
    const int lane = threadIdx.x & 63;
    float l = __uint_as_float(lmin[threadIdx.x * LSTRIDE]);
#pragma unroll
    for (int o = 32; o > 0; o >>= 1) l = fminf(l, __shfl_xor(l, o));
    if (lane == 0) hs[w] = 1.f / l;
    __syncthreads();
    if (threadIdx.x == 0) {
        float v = 0.f;
#pragma unroll
        for (int h = 0; h < 16; ++h) v += hs[h];
        *out = v * (1.f / NHEADS);
    }
}

extern "C" void kernel_launch(void* const* d_in, const int* in_sizes, int n_in,
                              void* d_out, int out_size, void* d_ws, size_t ws_size,
                              hipStream_t stream)
{
    const float* query = (const float*)d_in[0];
    const float* key   = (const float*)d_in[1];
    const float* value = (const float*)d_in[2];
    const float* mask  = (const float*)d_in[3];
    const float* Wq    = (const float*)d_in[4];
    const float* Wke   = (const float*)d_in[5];
    const float* Wkr   = (const float*)d_in[6];
    const float* Wv    = (const float*)d_in[7];
    const float* Wf    = (const float*)d_in[8];
    const float* u_p   = (const float*)d_in[9];
    const float* v_p   = (const float*)d_in[10];

    float* out_final = (float*)d_out;
    float* weights   = out_final + (i64)SEQ * DMODEL;
    float* loss      = weights + (i64)NHEADS * SEQ * SEQ;

    char* w = (char*)d_ws;
    u16* in_h = (u16*)w;               w += (i64)4 * IN_E * 2;
    u16* in_l = (u16*)w;               w += (i64)4 * IN_E * 2;
    u16* W_h  = (u16*)w;               w += (i64)5 * W_E * 2;
    u16* W_l  = (u16*)w;               w += (i64)5 * W_E * 2;
    u16* P_h  = (u16*)w;               w += (i64)4 * IN_E * 2;
    u16* P_l  = (u16*)w;               w += (i64)4 * IN_E * 2;
    u16* qv_h = (u16*)w;               w += (i64)IN_E * 2;
    u16* qv_l = (u16*)w;               w += (i64)IN_E * 2;
    u16* vvT_h = (u16*)w;              w += (i64)IN_E * 2;
    u16* vvT_l = (u16*)w;              w += (i64)IN_E * 2;
    u16* o_h  = (u16*)w;               w += (i64)IN_E * 2;
    u16* o_l  = (u16*)w;               w += (i64)IN_E * 2;
    unsigned int* lmin = (unsigned int*)w; w += (i64)NHEADS * LSLOTS * LSTRIDE * 4;
    const i64 fixed_bytes = (i64)(w - (char*)d_ws);
    const i64 gbytes = (i64)SEQ * SEQ * 4;
    const i64 avail = (i64)ws_size - fixed_bytes;
    float* G;
    int chunk;
    if (avail >= gbytes) {
        G = (float*)w;
        i64 ch = avail / gbytes;
        // cap at 4: per-chunk working set (W 67 + G 67 + vvT 17 + mask 16 MB)
        // stays L3-resident so the chunk's PV reads W as L3 hits
        chunk = ch > 4 ? 4 : (int)ch;
    } else {
        G = (float*)in_h;
        chunk = 2;
    }

    dim3 blk(256);
    init_kernel<<<dim3(1), dim3(1024), 0, stream>>>(lmin);

    SplitArgs sa;
    sa.src[0] = query; sa.dh[0] = in_h;           sa.dl[0] = in_l;           sa.n4[0] = IN_E / 4;
    sa.src[1] = key;   sa.dh[1] = in_h + IN_E;    sa.dl[1] = in_l + IN_E;    sa.n4[1] = IN_E / 4;
    sa.src[2] = value; sa.dh[2] = in_h + 2*IN_E;  sa.dl[2] = in_l + 2*IN_E;  sa.n4[2] = IN_E / 4;
    sa.src[3] = Wq;    sa.dh[3] = W_h;            sa.dl[3] = W_l;            sa.n4[3] = W_E / 4;
    sa.src[4] = Wke;   sa.dh[4] = W_h + W_E;      sa.dl[4] = W_l + W_E;      sa.n4[4] = W_E / 4;
    sa.src[5] = Wv;    sa.dh[5] = W_h + 2*W_E;    sa.dl[5] = W_l + 2*W_E;    sa.n4[5] = W_E / 4;
    sa.src[6] = Wkr;   sa.dh[6] = W_h + 3*W_E;    sa.dl[6] = W_l + 3*W_E;    sa.n4[6] = W_E / 4;
    sa.src[7] = Wf;    sa.dh[7] = W_h + 4*W_E;    sa.dl[7] = W_l + 4*W_E;    sa.n4[7] = W_E / 4;
    split_all<<<dim3(2048, 8), blk, 0, stream>>>(sa);
    posenc_split<<<dim3(IN_E / 256), blk, 0, stream>>>(in_h + 3*(i64)IN_E, in_l + 3*(i64)IN_E);

    {
        TNArgs p = {};
        p.Ah = in_h; p.Al = in_l; p.Bh = W_h; p.Bl = W_l;
        p.sAz = IN_E; p.sBz = W_E;
        p.O1h = P_h; p.O1l = P_l; p.O2h = qv_h; p.O2l = qv_l;
        p.b1 = u_p; p.b2 = v_p;
        p.K = DMODEL; p.mode = 1;
        mfma_tn128<<<dim3(DMODEL / 128, SEQ / 128, 4), blk, 0, stream>>>(p);
    }

    transpose_vv<<<dim3(SEQ / 64, NHEADS), blk, 0, stream>>>(
        P_h + 2*(i64)IN_E, P_l + 2*(i64)IN_E, vvT_h, vvT_l);

    // score + PV pipeline per chunk (chunk<=4):
    //  AC -> weights[h0..] (raw) ; BD -> G ; softmax -> weights ; PV reads the
    //  still-L3-resident weights chunk.
    for (int h0 = 0; h0 < NHEADS; h0 += chunk) {
        const int ch = (h0 + chunk <= NHEADS) ? chunk : (NHEADS - h0);
        {
            TNArgs p = {};
            p.Ah = P_h + (i64)h0 * HEAD_E; p.Al = P_l + (i64)h0 * HEAD_E;          // qu
            p.Bh = P_h + IN_E + (i64)h0 * HEAD_E; p.Bl = P_l + IN_E + (i64)h0 * HEAD_E; // kk
            p.sAz = HEAD_E; p.sBz = HEAD_E;
            p.Cf = weights + (i64)h0 * SEQ * SEQ; p.sCz = (i64)SEQ * SEQ; p.ldc = SEQ;
            p.K = DHEAD; p.mode = 0;
            mfma_tn128<<<dim3(SEQ / 128, SEQ / 128, ch), blk, 0, stream>>>(p);
        }
        {
            TNArgs p = {};
            p.Ah = qv_h + (i64)h0 * HEAD_E; p.Al = qv_l + (i64)h0 * HEAD_E;
            p.Bh = P_h + 3*(i64)IN_E + (i64)h0 * HEAD_E;
            p.Bl = P_l + 3*(i64)IN_E + (i64)h0 * HEAD_E;
            p.sAz = HEAD_E; p.sBz = HEAD_E;
            p.Cf = G; p.sCz = (i64)SEQ * SEQ; p.ldc = SEQ;
            p.K = DHEAD; p.mode = 0;
            mfma_tn128<<<dim3(SEQ / 128, SEQ / 128, ch), blk, 0, stream>>>(p);
        }
        softmax_rows<<<dim3(SEQ, ch), blk, 0, stream>>>(weights, G, mask, lmin, h0);
        mfma_pv<<<dim3(1, SEQ / 64, ch), blk, 0, stream>>>(
            weights + (i64)h0 * SEQ * SEQ,
            vvT_h + (i64)h0 * HEAD_E, vvT_l + (i64)h0 * HEAD_E,
            o_h, o_l, h0);
    }

    {
        TNArgs p = {};
        p.Ah = o_h; p.Al = o_l;
        p.Bh = W_h + 4*(i64)W_E; p.Bl = W_l + 4*(i64)W_E;
        p.sAz = 0; p.sBz = 0;
        p.Cf = out_final; p.sCz = 0; p.ldc = DMODEL;
        p.K = DMODEL; p.mode = 2;
        mfma_tn128<<<dim3(DMODEL / 128, SEQ / 128, 1), blk, 0, stream>>>(p);
    }

    loss_kernel<<<dim3(1), dim3(1024), 0, stream>>>(lmin, loss);
}

// Round 12
// 587.594 us; speedup vs baseline: 1.1900x; 1.1900x over previous
//
#include <hip/hip_runtime.h>
#include <math.h>

#define SEQ 2048
#define DMODEL 1024
#define NHEADS 16
#define DHEAD 64

// lmin sharding: 64 slices per head, each slice on its own 128B line
#define LSLOTS 64
#define LSTRIDE 32   // uints between slots (128 bytes)

typedef long long i64;
typedef unsigned short u16;
typedef __attribute__((ext_vector_type(4))) float f32x4;
typedef __attribute__((ext_vector_type(8))) short bf16x8;

#define IN_E  2097152   // 2048*1024
#define W_E   1048576   // 1024*1024
#define HEAD_E 131072   // 2048*64

__device__ inline u16 f2bf(float x) {                // RNE
    union { float f; unsigned u; } v; v.f = x;
    unsigned r = v.u + 0x7FFF + ((v.u >> 16) & 1);
    return (u16)(r >> 16);
}
__device__ inline float bf2f(u16 h) {
    union { unsigned u; float f; } v; v.u = ((unsigned)h) << 16;
    return v.f;
}

__device__ inline void gload16(const void* g, void* l) {
    __builtin_amdgcn_global_load_lds(
        (const __attribute__((address_space(1))) unsigned int*)g,
        (__attribute__((address_space(3))) unsigned int*)l, 16, 0, 0);
}

struct SplitArgs {
    const float* src[8];
    u16* dh[8];
    u16* dl[8];
    int n4[8];
};
__global__ __launch_bounds__(256)
void split_all(SplitArgs a)
{
    const int z = blockIdx.y;
    const int i = blockIdx.x * 256 + threadIdx.x;
    if (i >= a.n4[z]) return;
    const float4 x = ((const float4*)a.src[z])[i];
    u16 h0 = f2bf(x.x), h1 = f2bf(x.y), h2 = f2bf(x.z), h3 = f2bf(x.w);
    u16 l0 = f2bf(x.x - bf2f(h0)), l1 = f2bf(x.y - bf2f(h1));
    u16 l2 = f2bf(x.z - bf2f(h2)), l3 = f2bf(x.w - bf2f(h3));
    uint2 hh; hh.x = (unsigned)h0 | ((unsigned)h1 << 16); hh.y = (unsigned)h2 | ((unsigned)h3 << 16);
    uint2 ll; ll.x = (unsigned)l0 | ((unsigned)l1 << 16); ll.y = (unsigned)l2 | ((unsigned)l3 << 16);
    ((uint2*)a.dh[z])[i] = hh;
    ((uint2*)a.dl[z])[i] = ll;
}

__global__ __launch_bounds__(256)
void posenc_split(u16* __restrict__ dh, u16* __restrict__ dl)
{
    const int idx = blockIdx.x * 256 + threadIdx.x;
    const int f = idx >> 10;
    const int i = idx & 1023;
    const float P = (float)(SEQ - 1 - f);
    const float ex = (float)(i & ~1) * (1.f / 1024.f);
    const float dv = __expf(ex * -9.210340372f);   // 10000^-ex
    const float ang = P * dv;
    const float val = (i & 1) ? __cosf(ang) : __sinf(ang);
    const u16 hb = f2bf(val);
    dh[idx] = hb;
    dl[idx] = f2bf(val - bf2f(hb));
}

struct TNArgs {
    const u16 *Ah, *Al, *Bh, *Bl;
    i64 sAz, sBz;
    float* Cf; i64 sCz; int ldc;
    u16 *O1h, *O1l, *O2h, *O2l;
    const float *b1, *b2;
    int K, mode;
};

__global__ __launch_bounds__(256)
void mfma_tn128(TNArgs p)
{
    __shared__ __align__(16) u16 Ash[128 * 32];
    __shared__ __align__(16) u16 Asl[128 * 32];
    __shared__ __align__(16) u16 Bsh[128 * 32];
    __shared__ __align__(16) u16 Bsl[128 * 32];
    const int tid = threadIdx.x, wave = tid >> 6, lane = tid & 63;
    const int z = blockIdx.z;
    const i64 m0 = (i64)blockIdx.y * 128, n0 = (i64)blockIdx.x * 128;
    const int K = p.K;
    const u16* Abh = p.Ah + (i64)z * p.sAz;
    const u16* Abl = p.Al + (i64)z * p.sAz;
    const u16* Bbh = p.Bh + (i64)z * p.sBz;
    const u16* Bbl = p.Bl + (i64)z * p.sBz;
    const int r0 = tid >> 2, kc = (tid & 3) * 8;
    const int r1 = r0 + 64;
    u16* dA0 = &Ash[wave * 512];
    u16* dA1 = &Ash[2048 + wave * 512];
    u16* dA0l = &Asl[wave * 512];
    u16* dA1l = &Asl[2048 + wave * 512];
    u16* dB0 = &Bsh[wave * 512];
    u16* dB1 = &Bsh[2048 + wave * 512];
    u16* dB0l = &Bsl[wave * 512];
    u16* dB1l = &Bsl[2048 + wave * 512];
    const int wm = (wave >> 1) * 64, wn = (wave & 1) * 64;
    f32x4 acc[4][4] = {};

    for (int k0 = 0; k0 < K; k0 += 32) {
        __syncthreads();
        const i64 ga0 = (m0 + r0) * K + k0 + kc;
        const i64 ga1 = (m0 + r1) * K + k0 + kc;
        const i64 gb0 = (n0 + r0) * K + k0 + kc;
        const i64 gb1 = (n0 + r1) * K + k0 + kc;
        gload16(Abh + ga0, dA0);  gload16(Abh + ga1, dA1);
        gload16(Abl + ga0, dA0l); gload16(Abl + ga1, dA1l);
        gload16(Bbh + gb0, dB0);  gload16(Bbh + gb1, dB1);
        gload16(Bbl + gb0, dB0l); gload16(Bbl + gb1, dB1l);
        __syncthreads();
        const int fr = lane & 15, fk = (lane >> 4) * 8;
        bf16x8 fah[4], fal[4], fbh[4], fbl[4];
#pragma unroll
        for (int t = 0; t < 4; ++t) {
            fah[t] = *(const bf16x8*)&Ash[(wm + t * 16 + fr) * 32 + fk];
            fal[t] = *(const bf16x8*)&Asl[(wm + t * 16 + fr) * 32 + fk];
            fbh[t] = *(const bf16x8*)&Bsh[(wn + t * 16 + fr) * 32 + fk];
            fbl[t] = *(const bf16x8*)&Bsl[(wn + t * 16 + fr) * 32 + fk];
        }
#pragma unroll
        for (int mi = 0; mi < 4; ++mi)
#pragma unroll
            for (int ni = 0; ni < 4; ++ni) {
                acc[mi][ni] = __builtin_amdgcn_mfma_f32_16x16x32_bf16(fah[mi], fbh[ni], acc[mi][ni], 0, 0, 0);
                acc[mi][ni] = __builtin_amdgcn_mfma_f32_16x16x32_bf16(fah[mi], fbl[ni], acc[mi][ni], 0, 0, 0);
                acc[mi][ni] = __builtin_amdgcn_mfma_f32_16x16x32_bf16(fal[mi], fbh[ni], acc[mi][ni], 0, 0, 0);
            }
    }

    const int fr = lane & 15, fq = (lane >> 4) * 4;
    if (p.mode == 0) {
        float* C = p.Cf + (i64)z * p.sCz;
#pragma unroll
        for (int mi = 0; mi < 4; ++mi)
#pragma unroll
            for (int e = 0; e < 4; ++e) {
                const i64 row = m0 + wm + mi * 16 + fq + e;
#pragma unroll
                for (int ni = 0; ni < 4; ++ni)
                    C[row * p.ldc + n0 + wn + ni * 16 + fr] = acc[mi][ni][e];
            }
    } else if (p.mode == 1) {
        const i64 obase = (i64)z * IN_E;
#pragma unroll
        for (int mi = 0; mi < 4; ++mi)
#pragma unroll
            for (int e = 0; e < 4; ++e) {
                const i64 m = m0 + wm + mi * 16 + fq + e;
#pragma unroll
                for (int ni = 0; ni < 4; ++ni) {
                    const int c = (int)n0 + wn + ni * 16 + fr;
                    const int h = c >> 6, d = c & 63;
                    const i64 off = ((i64)h * SEQ + m) * DHEAD + d;
                    float v = acc[mi][ni][e];
                    if (z == 0) v += p.b1[c];
                    const u16 hb = f2bf(v);
                    const u16 lb = f2bf(v - bf2f(hb));
                    p.O1h[obase + off] = hb;
                    p.O1l[obase + off] = lb;
                    if (z == 0) {
                        const float v2 = acc[mi][ni][e] + p.b2[c];
                        const u16 hb2 = f2bf(v2);
                        const u16 lb2 = f2bf(v2 - bf2f(hb2));
                        p.O2h[off] = hb2;
                        p.O2l[off] = lb2;
                    }
                }
            }
    } else { // mode 2: exact GELU
        float* C = p.Cf;
#pragma unroll
        for (int mi = 0; mi < 4; ++mi)
#pragma unroll
            for (int e = 0; e < 4; ++e) {
                const i64 row = m0 + wm + mi * 16 + fq + e;
#pragma unroll
                for (int ni = 0; ni < 4; ++ni) {
                    const float x = acc[mi][ni][e];
                    C[row * p.ldc + n0 + wn + ni * 16 + fr] =
                        0.5f * x * (1.f + erff(x * 0.70710678118654752f));
                }
            }
    }
}

// ---------------------------------------------------------------------------
// FUSED AC + softmax: one block = (head, 16 score rows).
// Phase A: AC strip 16x2048 computed by MFMA straight into LDS (r5-verified
//   swapped-operand fragment mapping; only qa[2][2]=16 VGPRs persist -> no
//   spill, unlike r5's 48-VGPR variant). kk operands stream from L2
//   (512KB/head shared by 128 blocks).
// Phase B: wave-per-row softmax: AC from LDS + BD via verified 3-branch G
//   gather + mask; single coalesced W write. Deletes the 268MB raw-AC write
//   + 268MB re-read of the separate-AC pipeline.
// ---------------------------------------------------------------------------
__global__ __launch_bounds__(1024, 1)
void ac_softmax(const u16* __restrict__ QUh, const u16* __restrict__ QUl,
                const u16* __restrict__ KKh, const u16* __restrict__ KKl,
                const float* __restrict__ Gbase, const float* __restrict__ mask,
                float* __restrict__ Wbase, unsigned int* __restrict__ lmin, int h0)
{
    __shared__ __align__(16) float S[16][2052];
    const int tid = threadIdx.x, wave = tid >> 6, lane = tid & 63;
    const int hl = blockIdx.y;
    const int h = h0 + hl;
    const int r0 = blockIdx.x * 16;
    const i64 hb = (i64)h * HEAD_E;
    const int n = lane & 15;           // local row (B-frag col) in tile
    const int kc8 = (lane >> 4) * 8;   // k-chunk

    // persistent B-frags: qu rows r0+n (16 VGPRs)
    bf16x8 qa[2][2];
    {
        const i64 mo = hb + (i64)(r0 + n) * 64 + kc8;
#pragma unroll
        for (int ks = 0; ks < 2; ++ks) {
            qa[ks][0] = *(const bf16x8*)&QUh[mo + ks * 32];
            qa[ks][1] = *(const bf16x8*)&QUl[mo + ks * 32];
        }
    }

    // ---- Phase A: AC -> LDS (direct store; each (wave,tile) owns its slots)
    for (int t = wave; t < 128; t += 16) {
        const int ft = t * 16;
        const i64 ao = hb + (i64)(ft + n) * 64 + kc8;
        const bf16x8 a0h = *(const bf16x8*)&KKh[ao];
        const bf16x8 a0l = *(const bf16x8*)&KKl[ao];
        const bf16x8 a1h = *(const bf16x8*)&KKh[ao + 32];
        const bf16x8 a1l = *(const bf16x8*)&KKl[ao + 32];
        f32x4 a = {};
        a = __builtin_amdgcn_mfma_f32_16x16x32_bf16(a0h, qa[0][0], a, 0, 0, 0);
        a = __builtin_amdgcn_mfma_f32_16x16x32_bf16(a0h, qa[0][1], a, 0, 0, 0);
        a = __builtin_amdgcn_mfma_f32_16x16x32_bf16(a0l, qa[0][0], a, 0, 0, 0);
        a = __builtin_amdgcn_mfma_f32_16x16x32_bf16(a1h, qa[1][0], a, 0, 0, 0);
        a = __builtin_amdgcn_mfma_f32_16x16x32_bf16(a1h, qa[1][1], a, 0, 0, 0);
        a = __builtin_amdgcn_mfma_f32_16x16x32_bf16(a1l, qa[1][0], a, 0, 0, 0);
        const int fb = ft + (lane >> 4) * 4;
        *(f32x4*)&S[n][fb] = a;
    }
    __syncthreads();

    // ---- Phase B: wave = row softmax
    const int lr = wave;
    const int i = r0 + lr;
    const float* G = Gbase + (i64)hl * SEQ * SEQ;
    const i64 rowoff = (i64)i * SEQ;
    float sv[32];
    float mloc = -3.0e38f;
#pragma unroll
    for (int q = 0; q < 8; ++q) {
        const int j0 = q * 256 + lane * 4;
        const f32x4 ac = *(const f32x4*)&S[lr][j0];
        const float4 mk = *(const float4*)&mask[rowoff + j0];
        const float m4[4] = { mk.x, mk.y, mk.z, mk.w };
#pragma unroll
        for (int e = 0; e < 4; ++e) {
            const int j = j0 + e;
            float bd;
            if (j <= i)          bd = G[rowoff + (SEQ - 1 - i + j)];
            else if (j == i + 1) bd = 0.f;
            else                 bd = G[rowoff + SEQ + (j - i - 2)];
            const float v = (ac[e] + bd) * 0.03125f + m4[e];
            sv[q * 4 + e] = v;
            mloc = fmaxf(mloc, v);
        }
    }
#pragma unroll
    for (int o = 32; o > 0; o >>= 1) mloc = fmaxf(mloc, __shfl_xor(mloc, o));
    float lsum = 0.f;
#pragma unroll
    for (int q = 0; q < 32; ++q) { sv[q] = __expf(sv[q] - mloc); lsum += sv[q]; }
#pragma unroll
    for (int o = 32; o > 0; o >>= 1) lsum += __shfl_xor(lsum, o);
    const float inv = 1.f / lsum;
    float* Wh = Wbase + (i64)h * SEQ * SEQ;
#pragma unroll
    for (int q = 0; q < 8; ++q) {
        const int j0 = q * 256 + lane * 4;
        float4 ov;
        ov.x = sv[q * 4 + 0] * inv;
        ov.y = sv[q * 4 + 1] * inv;
        ov.z = sv[q * 4 + 2] * inv;
        ov.w = sv[q * 4 + 3] * inv;
        *(float4*)&Wh[rowoff + j0] = ov;
    }
    if (lane == 0)
        atomicMin(&lmin[(((unsigned)h << 6) + (i & (LSLOTS - 1))) * LSTRIDE],
                  __float_as_uint(lsum));
}

// ---------------------------------------------------------------------------
// PV: 64-row strips -> 512 blocks in ONE dispatch (full CU coverage; r11's
// per-chunk 128-block version re-introduced half-GPU idle -> reverted).
// ---------------------------------------------------------------------------
__global__ __launch_bounds__(256)
void mfma_pv(const float* __restrict__ Wgt, const u16* __restrict__ VTh,
             const u16* __restrict__ VTl, u16* __restrict__ Oh, u16* __restrict__ Ol)
{
    __shared__ __align__(16) float Asf[64 * 32];
    __shared__ __align__(16) u16 Bsh[64 * 32];
    __shared__ __align__(16) u16 Bsl[64 * 32];
    const int tid = threadIdx.x, wave = tid >> 6, lane = tid & 63;
    const int z = blockIdx.z;
    const i64 m0 = (i64)blockIdx.y * 64;
    const float* A = Wgt + (i64)z * SEQ * SEQ;
    const u16* Bh = VTh + (i64)z * HEAD_E;
    const u16* Bl = VTl + (i64)z * HEAD_E;
    const int ar = tid >> 3, akc = (tid & 7) * 4;
    const int br = tid >> 2, bkc = (tid & 3) * 8;
    const int wm = wave * 16;
    f32x4 acc[4] = {};

    for (int k0 = 0; k0 < SEQ; k0 += 32) {
        __syncthreads();
#pragma unroll
        for (int i = 0; i < 2; ++i)
            gload16(A + (m0 + ar + i * 32) * SEQ + k0 + akc, &Asf[(i * 256 + wave * 64) * 4]);
        gload16(Bh + (i64)br * SEQ + k0 + bkc, &Bsh[wave * 512]);
        gload16(Bl + (i64)br * SEQ + k0 + bkc, &Bsl[wave * 512]);
        __syncthreads();
        const int fr = lane & 15, fk = (lane >> 4) * 8;
        bf16x8 fbh[4], fbl[4];
#pragma unroll
        for (int t = 0; t < 4; ++t) {
            fbh[t] = *(const bf16x8*)&Bsh[(t * 16 + fr) * 32 + fk];
            fbl[t] = *(const bf16x8*)&Bsl[(t * 16 + fr) * 32 + fk];
        }
        const float4 x0 = *(const float4*)&Asf[(wm + fr) * 32 + fk];
        const float4 x1 = *(const float4*)&Asf[(wm + fr) * 32 + fk + 4];
        float av[8] = { x0.x, x0.y, x0.z, x0.w, x1.x, x1.y, x1.z, x1.w };
        bf16x8 ah, al;
#pragma unroll
        for (int j = 0; j < 8; ++j) {
            union { float f; unsigned u; } v; v.f = av[j];
            const u16 hb = (u16)(v.u >> 16);
            union { unsigned u; float f; } fh; fh.u = v.u & 0xFFFF0000u;
            union { float f; unsigned u; } rm; rm.f = av[j] - fh.f;
            ah[j] = (short)hb;
            al[j] = (short)(u16)(rm.u >> 16);
        }
#pragma unroll
        for (int ni = 0; ni < 4; ++ni) {
            acc[ni] = __builtin_amdgcn_mfma_f32_16x16x32_bf16(ah, fbh[ni], acc[ni], 0, 0, 0);
            acc[ni] = __builtin_amdgcn_mfma_f32_16x16x32_bf16(ah, fbl[ni], acc[ni], 0, 0, 0);
            acc[ni] = __builtin_amdgcn_mfma_f32_16x16x32_bf16(al, fbh[ni], acc[ni], 0, 0, 0);
        }
    }

    const int fr = lane & 15, fq = (lane >> 4) * 4;
#pragma unroll
    for (int e = 0; e < 4; ++e) {
        const i64 m = m0 + wm + fq + e;
#pragma unroll
        for (int ni = 0; ni < 4; ++ni) {
            const int c = z * 64 + ni * 16 + fr;
            const float v = acc[ni][e];
            const u16 hb = f2bf(v);
            Oh[m * DMODEL + c] = hb;
            Ol[m * DMODEL + c] = f2bf(v - bf2f(hb));
        }
    }
}

__global__ __launch_bounds__(256)
void transpose_vv(const u16* __restrict__ vh, const u16* __restrict__ vl,
                  u16* __restrict__ th, u16* __restrict__ tl)
{
    __shared__ u16 tile[64][65];
    const int tid = threadIdx.x;
    const int h = blockIdx.y, f0 = blockIdx.x * 64;
    const i64 src = ((i64)h * SEQ + f0) * DHEAD;
    const i64 dst = (i64)h * HEAD_E + f0;
#pragma unroll
    for (int i = 0; i < 16; ++i) {
        const int idx = i * 256 + tid;
        const int r = idx >> 6, c = idx & 63;
        tile[c][r] = vh[src + (i64)r * 64 + c];
    }
    __syncthreads();
#pragma unroll
    for (int i = 0; i < 16; ++i) {
        const int idx = i * 256 + tid;
        const int d = idx >> 6, fl = idx & 63;
        th[dst + (i64)d * SEQ + fl] = tile[d][fl];
    }
    __syncthreads();
#pragma unroll
    for (int i = 0; i < 16; ++i) {
        const int idx = i * 256 + tid;
        const int r = idx >> 6, c = idx & 63;
        tile[c][r] = vl[src + (i64)r * 64 + c];
    }
    __syncthreads();
#pragma unroll
    for (int i = 0; i < 16; ++i) {
        const int idx = i * 256 + tid;
        const int d = idx >> 6, fl = idx & 63;
        tl[dst + (i64)d * SEQ + fl] = tile[d][fl];
    }
}

__global__ __launch_bounds__(1024)
void init_kernel(unsigned int* __restrict__ lmin)
{
    lmin[threadIdx.x * LSTRIDE] = 0x7F7FFFFFu;
}

__global__ __launch_bounds__(1024)
void loss_kernel(const unsigned int* __restrict__ lmin, float* __restrict__ out)
{
    __shared__ float hs[16];
    const int w = threadIdx.x >> 6;
    const int lane = threadIdx.x & 63;
    float l = __uint_as_float(lmin[threadIdx.x * LSTRIDE]);
#pragma unroll
    for (int o = 32; o > 0; o >>= 1) l = fminf(l, __shfl_xor(l, o));
    if (lane == 0) hs[w] = 1.f / l;
    __syncthreads();
    if (threadIdx.x == 0) {
        float v = 0.f;
#pragma unroll
        for (int h = 0; h < 16; ++h) v += hs[h];
        *out = v * (1.f / NHEADS);
    }
}

extern "C" void kernel_launch(void* const* d_in, const int* in_sizes, int n_in,
                              void* d_out, int out_size, void* d_ws, size_t ws_size,
                              hipStream_t stream)
{
    const float* query = (const float*)d_in[0];
    const float* key   = (const float*)d_in[1];
    const float* value = (const float*)d_in[2];
    const float* mask  = (const float*)d_in[3];
    const float* Wq    = (const float*)d_in[4];
    const float* Wke   = (const float*)d_in[5];
    const float* Wkr   = (const float*)d_in[6];
    const float* Wv    = (const float*)d_in[7];
    const float* Wf    = (const float*)d_in[8];
    const float* u_p   = (const float*)d_in[9];
    const float* v_p   = (const float*)d_in[10];

    float* out_final = (float*)d_out;
    float* weights   = out_final + (i64)SEQ * DMODEL;
    float* loss      = weights + (i64)NHEADS * SEQ * SEQ;

    char* w = (char*)d_ws;
    u16* in_h = (u16*)w;               w += (i64)4 * IN_E * 2;
    u16* in_l = (u16*)w;               w += (i64)4 * IN_E * 2;
    u16* W_h  = (u16*)w;               w += (i64)5 * W_E * 2;
    u16* W_l  = (u16*)w;               w += (i64)5 * W_E * 2;
    u16* P_h  = (u16*)w;               w += (i64)4 * IN_E * 2;
    u16* P_l  = (u16*)w;               w += (i64)4 * IN_E * 2;
    u16* qv_h = (u16*)w;               w += (i64)IN_E * 2;
    u16* qv_l = (u16*)w;               w += (i64)IN_E * 2;
    u16* vvT_h = (u16*)w;              w += (i64)IN_E * 2;
    u16* vvT_l = (u16*)w;              w += (i64)IN_E * 2;
    u16* o_h  = (u16*)w;               w += (i64)IN_E * 2;
    u16* o_l  = (u16*)w;               w += (i64)IN_E * 2;
    unsigned int* lmin = (unsigned int*)w; w += (i64)NHEADS * LSLOTS * LSTRIDE * 4;
    const i64 fixed_bytes = (i64)(w - (char*)d_ws);
    const i64 gbytes = (i64)SEQ * SEQ * 4;
    const i64 avail = (i64)ws_size - fixed_bytes;
    float* G;
    int chunk;
    if (avail >= gbytes) {
        G = (float*)w;
        i64 ch = avail / gbytes;
        chunk = ch > 16 ? 16 : (int)ch;
    } else {
        G = (float*)in_h;
        chunk = 2;
    }

    dim3 blk(256);
    init_kernel<<<dim3(1), dim3(1024), 0, stream>>>(lmin);

    SplitArgs sa;
    sa.src[0] = query; sa.dh[0] = in_h;           sa.dl[0] = in_l;           sa.n4[0] = IN_E / 4;
    sa.src[1] = key;   sa.dh[1] = in_h + IN_E;    sa.dl[1] = in_l + IN_E;    sa.n4[1] = IN_E / 4;
    sa.src[2] = value; sa.dh[2] = in_h + 2*IN_E;  sa.dl[2] = in_l + 2*IN_E;  sa.n4[2] = IN_E / 4;
    sa.src[3] = Wq;    sa.dh[3] = W_h;            sa.dl[3] = W_l;            sa.n4[3] = W_E / 4;
    sa.src[4] = Wke;   sa.dh[4] = W_h + W_E;      sa.dl[4] = W_l + W_E;      sa.n4[4] = W_E / 4;
    sa.src[5] = Wv;    sa.dh[5] = W_h + 2*W_E;    sa.dl[5] = W_l + 2*W_E;    sa.n4[5] = W_E / 4;
    sa.src[6] = Wkr;   sa.dh[6] = W_h + 3*W_E;    sa.dl[6] = W_l + 3*W_E;    sa.n4[6] = W_E / 4;
    sa.src[7] = Wf;    sa.dh[7] = W_h + 4*W_E;    sa.dl[7] = W_l + 4*W_E;    sa.n4[7] = W_E / 4;
    split_all<<<dim3(2048, 8), blk, 0, stream>>>(sa);
    posenc_split<<<dim3(IN_E / 256), blk, 0, stream>>>(in_h + 3*(i64)IN_E, in_l + 3*(i64)IN_E);

    {
        TNArgs p = {};
        p.Ah = in_h; p.Al = in_l; p.Bh = W_h; p.Bl = W_l;
        p.sAz = IN_E; p.sBz = W_E;
        p.O1h = P_h; p.O1l = P_l; p.O2h = qv_h; p.O2l = qv_l;
        p.b1 = u_p; p.b2 = v_p;
        p.K = DMODEL; p.mode = 1;
        mfma_tn128<<<dim3(DMODEL / 128, SEQ / 128, 4), blk, 0, stream>>>(p);
    }

    transpose_vv<<<dim3(SEQ / 64, NHEADS), blk, 0, stream>>>(
        P_h + 2*(i64)IN_E, P_l + 2*(i64)IN_E, vvT_h, vvT_l);

    // score pipeline per chunk: BD -> G (mode-0), then fused AC+softmax
    // (AC computed in-LDS via MFMA; no raw-AC HBM round trip).
    for (int h0 = 0; h0 < NHEADS; h0 += chunk) {
        const int ch = (h0 + chunk <= NHEADS) ? chunk : (NHEADS - h0);
        {
            TNArgs p = {};
            p.Ah = qv_h + (i64)h0 * HEAD_E; p.Al = qv_l + (i64)h0 * HEAD_E;
            p.Bh = P_h + 3*(i64)IN_E + (i64)h0 * HEAD_E;
            p.Bl = P_l + 3*(i64)IN_E + (i64)h0 * HEAD_E;
            p.sAz = HEAD_E; p.sBz = HEAD_E;
            p.Cf = G; p.sCz = (i64)SEQ * SEQ; p.ldc = SEQ;
            p.K = DHEAD; p.mode = 0;
            mfma_tn128<<<dim3(SEQ / 128, SEQ / 128, ch), blk, 0, stream>>>(p);
        }
        ac_softmax<<<dim3(SEQ / 16, ch), dim3(1024), 0, stream>>>(
            P_h, P_l,                       // qu (indexed by absolute head inside)
            P_h + IN_E, P_l + IN_E,         // kk
            G, mask, weights, lmin, h0);
    }

    // PV (single dispatch, 512 blocks, full CU coverage)
    mfma_pv<<<dim3(1, SEQ / 64, NHEADS), blk, 0, stream>>>(weights, vvT_h, vvT_l, o_h, o_l);

    {
        TNArgs p = {};
        p.Ah = o_h; p.Al = o_l;
        p.Bh = W_h + 4*(i64)W_E; p.Bl = W_l + 4*(i64)W_E;
        p.sAz = 0; p.sBz = 0;
        p.Cf = out_final; p.sCz = 0; p.ldc = DMODEL;
        p.K = DMODEL; p.mode = 2;
        mfma_tn128<<<dim3(DMODEL / 128, SEQ / 128, 1), blk, 0, stream>>>(p);
    }

    loss_kernel<<<dim3(1), dim3(1024), 0, stream>>>(lmin, loss);
}

// Round 13
// 569.702 us; speedup vs baseline: 1.2273x; 1.0314x over previous
//
#include <hip/hip_runtime.h>
#include <math.h>

#define SEQ 2048
#define DMODEL 1024
#define NHEADS 16
#define DHEAD 64

// lmin sharding: 64 slices per head, each slice on its own 128B line
#define LSLOTS 64
#define LSTRIDE 32   // uints between slots (128 bytes)

typedef long long i64;
typedef unsigned short u16;
typedef __attribute__((ext_vector_type(4))) float f32x4;
typedef __attribute__((ext_vector_type(8))) short bf16x8;

#define IN_E  2097152   // 2048*1024
#define W_E   1048576   // 1024*1024
#define HEAD_E 131072   // 2048*64

__device__ inline u16 f2bf(float x) {                // RNE
    union { float f; unsigned u; } v; v.f = x;
    unsigned r = v.u + 0x7FFF + ((v.u >> 16) & 1);
    return (u16)(r >> 16);
}
__device__ inline float bf2f(u16 h) {
    union { unsigned u; float f; } v; v.u = ((unsigned)h) << 16;
    return v.f;
}

__device__ inline void gload16(const void* g, void* l) {
    __builtin_amdgcn_global_load_lds(
        (const __attribute__((address_space(1))) unsigned int*)g,
        (__attribute__((address_space(3))) unsigned int*)l, 16, 0, 0);
}

struct SplitArgs {
    const float* src[8];
    u16* dh[8];
    u16* dl[8];
    int n4[8];
};
__global__ __launch_bounds__(256)
void split_all(SplitArgs a)
{
    const int z = blockIdx.y;
    const int i = blockIdx.x * 256 + threadIdx.x;
    if (i >= a.n4[z]) return;
    const float4 x = ((const float4*)a.src[z])[i];
    u16 h0 = f2bf(x.x), h1 = f2bf(x.y), h2 = f2bf(x.z), h3 = f2bf(x.w);
    u16 l0 = f2bf(x.x - bf2f(h0)), l1 = f2bf(x.y - bf2f(h1));
    u16 l2 = f2bf(x.z - bf2f(h2)), l3 = f2bf(x.w - bf2f(h3));
    uint2 hh; hh.x = (unsigned)h0 | ((unsigned)h1 << 16); hh.y = (unsigned)h2 | ((unsigned)h3 << 16);
    uint2 ll; ll.x = (unsigned)l0 | ((unsigned)l1 << 16); ll.y = (unsigned)l2 | ((unsigned)l3 << 16);
    ((uint2*)a.dh[z])[i] = hh;
    ((uint2*)a.dl[z])[i] = ll;
}

__global__ __launch_bounds__(256)
void posenc_split(u16* __restrict__ dh, u16* __restrict__ dl)
{
    const int idx = blockIdx.x * 256 + threadIdx.x;
    const int f = idx >> 10;
    const int i = idx & 1023;
    const float P = (float)(SEQ - 1 - f);
    const float ex = (float)(i & ~1) * (1.f / 1024.f);
    const float dv = __expf(ex * -9.210340372f);   // 10000^-ex
    const float ang = P * dv;
    const float val = (i & 1) ? __cosf(ang) : __sinf(ang);
    const u16 hb = f2bf(val);
    dh[idx] = hb;
    dl[idx] = f2bf(val - bf2f(hb));
}

struct TNArgs {
    const u16 *Ah, *Al, *Bh, *Bl;
    i64 sAz, sBz;
    float* Cf; i64 sCz; int ldc;
    u16 *O1h, *O1l, *O2h, *O2l;
    const float *b1, *b2;
    int K, mode;
};

__global__ __launch_bounds__(256)
void mfma_tn128(TNArgs p)
{
    __shared__ __align__(16) u16 Ash[128 * 32];
    __shared__ __align__(16) u16 Asl[128 * 32];
    __shared__ __align__(16) u16 Bsh[128 * 32];
    __shared__ __align__(16) u16 Bsl[128 * 32];
    const int tid = threadIdx.x, wave = tid >> 6, lane = tid & 63;
    const int z = blockIdx.z;
    const i64 m0 = (i64)blockIdx.y * 128, n0 = (i64)blockIdx.x * 128;
    const int K = p.K;
    const u16* Abh = p.Ah + (i64)z * p.sAz;
    const u16* Abl = p.Al + (i64)z * p.sAz;
    const u16* Bbh = p.Bh + (i64)z * p.sBz;
    const u16* Bbl = p.Bl + (i64)z * p.sBz;
    const int r0 = tid >> 2, kc = (tid & 3) * 8;
    const int r1 = r0 + 64;
    u16* dA0 = &Ash[wave * 512];
    u16* dA1 = &Ash[2048 + wave * 512];
    u16* dA0l = &Asl[wave * 512];
    u16* dA1l = &Asl[2048 + wave * 512];
    u16* dB0 = &Bsh[wave * 512];
    u16* dB1 = &Bsh[2048 + wave * 512];
    u16* dB0l = &Bsl[wave * 512];
    u16* dB1l = &Bsl[2048 + wave * 512];
    const int wm = (wave >> 1) * 64, wn = (wave & 1) * 64;
    f32x4 acc[4][4] = {};

    for (int k0 = 0; k0 < K; k0 += 32) {
        __syncthreads();
        const i64 ga0 = (m0 + r0) * K + k0 + kc;
        const i64 ga1 = (m0 + r1) * K + k0 + kc;
        const i64 gb0 = (n0 + r0) * K + k0 + kc;
        const i64 gb1 = (n0 + r1) * K + k0 + kc;
        gload16(Abh + ga0, dA0);  gload16(Abh + ga1, dA1);
        gload16(Abl + ga0, dA0l); gload16(Abl + ga1, dA1l);
        gload16(Bbh + gb0, dB0);  gload16(Bbh + gb1, dB1);
        gload16(Bbl + gb0, dB0l); gload16(Bbl + gb1, dB1l);
        __syncthreads();
        const int fr = lane & 15, fk = (lane >> 4) * 8;
        bf16x8 fah[4], fal[4], fbh[4], fbl[4];
#pragma unroll
        for (int t = 0; t < 4; ++t) {
            fah[t] = *(const bf16x8*)&Ash[(wm + t * 16 + fr) * 32 + fk];
            fal[t] = *(const bf16x8*)&Asl[(wm + t * 16 + fr) * 32 + fk];
            fbh[t] = *(const bf16x8*)&Bsh[(wn + t * 16 + fr) * 32 + fk];
            fbl[t] = *(const bf16x8*)&Bsl[(wn + t * 16 + fr) * 32 + fk];
        }
#pragma unroll
        for (int mi = 0; mi < 4; ++mi)
#pragma unroll
            for (int ni = 0; ni < 4; ++ni) {
                acc[mi][ni] = __builtin_amdgcn_mfma_f32_16x16x32_bf16(fah[mi], fbh[ni], acc[mi][ni], 0, 0, 0);
                acc[mi][ni] = __builtin_amdgcn_mfma_f32_16x16x32_bf16(fah[mi], fbl[ni], acc[mi][ni], 0, 0, 0);
                acc[mi][ni] = __builtin_amdgcn_mfma_f32_16x16x32_bf16(fal[mi], fbh[ni], acc[mi][ni], 0, 0, 0);
            }
    }

    const int fr = lane & 15, fq = (lane >> 4) * 4;
    if (p.mode == 0) {
        float* C = p.Cf + (i64)z * p.sCz;
#pragma unroll
        for (int mi = 0; mi < 4; ++mi)
#pragma unroll
            for (int e = 0; e < 4; ++e) {
                const i64 row = m0 + wm + mi * 16 + fq + e;
#pragma unroll
                for (int ni = 0; ni < 4; ++ni)
                    C[row * p.ldc + n0 + wn + ni * 16 + fr] = acc[mi][ni][e];
            }
    } else if (p.mode == 1) {
        const i64 obase = (i64)z * IN_E;
#pragma unroll
        for (int mi = 0; mi < 4; ++mi)
#pragma unroll
            for (int e = 0; e < 4; ++e) {
                const i64 m = m0 + wm + mi * 16 + fq + e;
#pragma unroll
                for (int ni = 0; ni < 4; ++ni) {
                    const int c = (int)n0 + wn + ni * 16 + fr;
                    const int h = c >> 6, d = c & 63;
                    const i64 off = ((i64)h * SEQ + m) * DHEAD + d;
                    float v = acc[mi][ni][e];
                    if (z == 0) v += p.b1[c];
                    const u16 hb = f2bf(v);
                    const u16 lb = f2bf(v - bf2f(hb));
                    p.O1h[obase + off] = hb;
                    p.O1l[obase + off] = lb;
                    if (z == 0) {
                        const float v2 = acc[mi][ni][e] + p.b2[c];
                        const u16 hb2 = f2bf(v2);
                        const u16 lb2 = f2bf(v2 - bf2f(hb2));
                        p.O2h[off] = hb2;
                        p.O2l[off] = lb2;
                    }
                }
            }
    } else { // mode 2: exact GELU
        float* C = p.Cf;
#pragma unroll
        for (int mi = 0; mi < 4; ++mi)
#pragma unroll
            for (int e = 0; e < 4; ++e) {
                const i64 row = m0 + wm + mi * 16 + fq + e;
#pragma unroll
                for (int ni = 0; ni < 4; ++ni) {
                    const float x = acc[mi][ni][e];
                    C[row * p.ldc + n0 + wn + ni * 16 + fr] =
                        0.5f * x * (1.f + erff(x * 0.70710678118654752f));
                }
            }
    }
}

// ---------------------------------------------------------------------------
// PV: 64-row strips -> 512 blocks, full 256-CU coverage (r9 fix: 256-row
// strips gave only 128 blocks = half the GPU idle).
// ---------------------------------------------------------------------------
__global__ __launch_bounds__(256)
void mfma_pv(const float* __restrict__ Wgt, const u16* __restrict__ VTh,
             const u16* __restrict__ VTl, u16* __restrict__ Oh, u16* __restrict__ Ol)
{
    __shared__ __align__(16) float Asf[64 * 32];
    __shared__ __align__(16) u16 Bsh[64 * 32];
    __shared__ __align__(16) u16 Bsl[64 * 32];
    const int tid = threadIdx.x, wave = tid >> 6, lane = tid & 63;
    const int z = blockIdx.z;
    const i64 m0 = (i64)blockIdx.y * 64;
    const float* A = Wgt + (i64)z * SEQ * SEQ;
    const u16* Bh = VTh + (i64)z * HEAD_E;
    const u16* Bl = VTl + (i64)z * HEAD_E;
    const int ar = tid >> 3, akc = (tid & 7) * 4;
    const int br = tid >> 2, bkc = (tid & 3) * 8;
    const int wm = wave * 16;
    f32x4 acc[4] = {};

    for (int k0 = 0; k0 < SEQ; k0 += 32) {
        __syncthreads();
#pragma unroll
        for (int i = 0; i < 2; ++i)
            gload16(A + (m0 + ar + i * 32) * SEQ + k0 + akc, &Asf[(i * 256 + wave * 64) * 4]);
        gload16(Bh + (i64)br * SEQ + k0 + bkc, &Bsh[wave * 512]);
        gload16(Bl + (i64)br * SEQ + k0 + bkc, &Bsl[wave * 512]);
        __syncthreads();
        const int fr = lane & 15, fk = (lane >> 4) * 8;
        bf16x8 fbh[4], fbl[4];
#pragma unroll
        for (int t = 0; t < 4; ++t) {
            fbh[t] = *(const bf16x8*)&Bsh[(t * 16 + fr) * 32 + fk];
            fbl[t] = *(const bf16x8*)&Bsl[(t * 16 + fr) * 32 + fk];
        }
        const float4 x0 = *(const float4*)&Asf[(wm + fr) * 32 + fk];
        const float4 x1 = *(const float4*)&Asf[(wm + fr) * 32 + fk + 4];
        float av[8] = { x0.x, x0.y, x0.z, x0.w, x1.x, x1.y, x1.z, x1.w };
        bf16x8 ah, al;
#pragma unroll
        for (int j = 0; j < 8; ++j) {
            union { float f; unsigned u; } v; v.f = av[j];
            const u16 hb = (u16)(v.u >> 16);
            union { unsigned u; float f; } fh; fh.u = v.u & 0xFFFF0000u;
            union { float f; unsigned u; } rm; rm.f = av[j] - fh.f;
            ah[j] = (short)hb;
            al[j] = (short)(u16)(rm.u >> 16);
        }
#pragma unroll
        for (int ni = 0; ni < 4; ++ni) {
            acc[ni] = __builtin_amdgcn_mfma_f32_16x16x32_bf16(ah, fbh[ni], acc[ni], 0, 0, 0);
            acc[ni] = __builtin_amdgcn_mfma_f32_16x16x32_bf16(ah, fbl[ni], acc[ni], 0, 0, 0);
            acc[ni] = __builtin_amdgcn_mfma_f32_16x16x32_bf16(al, fbh[ni], acc[ni], 0, 0, 0);
        }
    }

    const int fr = lane & 15, fq = (lane >> 4) * 4;
#pragma unroll
    for (int e = 0; e < 4; ++e) {
        const i64 m = m0 + wm + fq + e;
#pragma unroll
        for (int ni = 0; ni < 4; ++ni) {
            const int c = z * 64 + ni * 16 + fr;
            const float v = acc[ni][e];
            const u16 hb = f2bf(v);
            Oh[m * DMODEL + c] = hb;
            Ol[m * DMODEL + c] = f2bf(v - bf2f(hb));
        }
    }
}

__global__ __launch_bounds__(256)
void transpose_vv(const u16* __restrict__ vh, const u16* __restrict__ vl,
                  u16* __restrict__ th, u16* __restrict__ tl)
{
    __shared__ u16 tile[64][65];
    const int tid = threadIdx.x;
    const int h = blockIdx.y, f0 = blockIdx.x * 64;
    const i64 src = ((i64)h * SEQ + f0) * DHEAD;
    const i64 dst = (i64)h * HEAD_E + f0;
#pragma unroll
    for (int i = 0; i < 16; ++i) {
        const int idx = i * 256 + tid;
        const int r = idx >> 6, c = idx & 63;
        tile[c][r] = vh[src + (i64)r * 64 + c];
    }
    __syncthreads();
#pragma unroll
    for (int i = 0; i < 16; ++i) {
        const int idx = i * 256 + tid;
        const int d = idx >> 6, fl = idx & 63;
        th[dst + (i64)d * SEQ + fl] = tile[d][fl];
    }
    __syncthreads();
#pragma unroll
    for (int i = 0; i < 16; ++i) {
        const int idx = i * 256 + tid;
        const int r = idx >> 6, c = idx & 63;
        tile[c][r] = vl[src + (i64)r * 64 + c];
    }
    __syncthreads();
#pragma unroll
    for (int i = 0; i < 16; ++i) {
        const int idx = i * 256 + tid;
        const int d = idx >> 6, fl = idx & 63;
        tl[dst + (i64)d * SEQ + fl] = tile[d][fl];
    }
}

// ---------------------------------------------------------------------------
// Row softmax: block-per-row, 8 elems/thread, shfl+LDS reduce, sharded
// atomicMin. Measured 3.87 TB/s across three structural variants — within
// ~10% of the realistic mixed-stream (3R+1W) HBM ceiling for this chip.
// ---------------------------------------------------------------------------
__global__ __launch_bounds__(256)
void softmax_rows(float* __restrict__ Wbase, const float* __restrict__ Gbase,
                  const float* __restrict__ mask, unsigned int* __restrict__ lmin, int h0)
{
    __shared__ float red[4];
    const int hl = blockIdx.y;
    float* Wh = Wbase + (i64)(h0 + hl) * SEQ * SEQ;
    const float* G = Gbase + (i64)hl * SEQ * SEQ;
    const int i = blockIdx.x;
    const int tx = threadIdx.x;
    const i64 rowoff = (i64)i * SEQ;
    float s[8];
    float mloc = -3.0e38f;
#pragma unroll
    for (int r = 0; r < 8; ++r) {
        const int j = tx + (r << 8);
        float bd;
        if (j <= i)          bd = G[rowoff + (SEQ - 1 - i + j)];
        else if (j == i + 1) bd = 0.f;
        else                 bd = G[rowoff + SEQ + (j - i - 2)];
        const float v = (Wh[rowoff + j] + bd) * 0.03125f + mask[rowoff + j];
        s[r] = v;
        mloc = fmaxf(mloc, v);
    }
#pragma unroll
    for (int o = 32; o > 0; o >>= 1) mloc = fmaxf(mloc, __shfl_xor(mloc, o));
    if ((tx & 63) == 0) red[tx >> 6] = mloc;
    __syncthreads();
    const float m = fmaxf(fmaxf(red[0], red[1]), fmaxf(red[2], red[3]));
    __syncthreads();
    float lsum = 0.f;
#pragma unroll
    for (int r = 0; r < 8; ++r) { s[r] = __expf(s[r] - m); lsum += s[r]; }
#pragma unroll
    for (int o = 32; o > 0; o >>= 1) lsum += __shfl_xor(lsum, o);
    if ((tx & 63) == 0) red[tx >> 6] = lsum;
    __syncthreads();
    const float l = red[0] + red[1] + red[2] + red[3];
    const float inv = 1.f / l;
#pragma unroll
    for (int r = 0; r < 8; ++r) Wh[rowoff + tx + (r << 8)] = s[r] * inv;
    if (tx == 0)
        atomicMin(&lmin[(((h0 + hl) << 6) + (i & (LSLOTS - 1))) * LSTRIDE],
                  __float_as_uint(l));
}

__global__ __launch_bounds__(1024)
void init_kernel(unsigned int* __restrict__ lmin)
{
    lmin[threadIdx.x * LSTRIDE] = 0x7F7FFFFFu;
}

__global__ __launch_bounds__(1024)
void loss_kernel(const unsigned int* __restrict__ lmin, float* __restrict__ out)
{
    __shared__ float hs[16];
    const int w = threadIdx.x >> 6;
    const int lane = threadIdx.x & 63;
    float l = __uint_as_float(lmin[threadIdx.x * LSTRIDE]);
#pragma unroll
    for (int o = 32; o > 0; o >>= 1) l = fminf(l, __shfl_xor(l, o));
    if (lane == 0) hs[w] = 1.f / l;
    __syncthreads();
    if (threadIdx.x == 0) {
        float v = 0.f;
#pragma unroll
        for (int h = 0; h < 16; ++h) v += hs[h];
        *out = v * (1.f / NHEADS);
    }
}

extern "C" void kernel_launch(void* const* d_in, const int* in_sizes, int n_in,
                              void* d_out, int out_size, void* d_ws, size_t ws_size,
                              hipStream_t stream)
{
    const float* query = (const float*)d_in[0];
    const float* key   = (const float*)d_in[1];
    const float* value = (const float*)d_in[2];
    const float* mask  = (const float*)d_in[3];
    const float* Wq    = (const float*)d_in[4];
    const float* Wke   = (const float*)d_in[5];
    const float* Wkr   = (const float*)d_in[6];
    const float* Wv    = (const float*)d_in[7];
    const float* Wf    = (const float*)d_in[8];
    const float* u_p   = (const float*)d_in[9];
    const float* v_p   = (const float*)d_in[10];

    float* out_final = (float*)d_out;
    float* weights   = out_final + (i64)SEQ * DMODEL;
    float* loss      = weights + (i64)NHEADS * SEQ * SEQ;

    char* w = (char*)d_ws;
    u16* in_h = (u16*)w;               w += (i64)4 * IN_E * 2;
    u16* in_l = (u16*)w;               w += (i64)4 * IN_E * 2;
    u16* W_h  = (u16*)w;               w += (i64)5 * W_E * 2;
    u16* W_l  = (u16*)w;               w += (i64)5 * W_E * 2;
    u16* P_h  = (u16*)w;               w += (i64)4 * IN_E * 2;
    u16* P_l  = (u16*)w;               w += (i64)4 * IN_E * 2;
    u16* qv_h = (u16*)w;               w += (i64)IN_E * 2;
    u16* qv_l = (u16*)w;               w += (i64)IN_E * 2;
    u16* vvT_h = (u16*)w;              w += (i64)IN_E * 2;
    u16* vvT_l = (u16*)w;              w += (i64)IN_E * 2;
    u16* o_h  = (u16*)w;               w += (i64)IN_E * 2;
    u16* o_l  = (u16*)w;               w += (i64)IN_E * 2;
    unsigned int* lmin = (unsigned int*)w; w += (i64)NHEADS * LSLOTS * LSTRIDE * 4;
    const i64 fixed_bytes = (i64)(w - (char*)d_ws);
    const i64 gbytes = (i64)SEQ * SEQ * 4;
    const i64 avail = (i64)ws_size - fixed_bytes;
    float* G;
    int chunk;
    if (avail >= gbytes) {
        G = (float*)w;
        i64 ch = avail / gbytes;
        chunk = ch > 16 ? 16 : (int)ch;
    } else {
        G = (float*)in_h;
        chunk = 2;
    }

    dim3 blk(256);
    init_kernel<<<dim3(1), dim3(1024), 0, stream>>>(lmin);

    SplitArgs sa;
    sa.src[0] = query; sa.dh[0] = in_h;           sa.dl[0] = in_l;           sa.n4[0] = IN_E / 4;
    sa.src[1] = key;   sa.dh[1] = in_h + IN_E;    sa.dl[1] = in_l + IN_E;    sa.n4[1] = IN_E / 4;
    sa.src[2] = value; sa.dh[2] = in_h + 2*IN_E;  sa.dl[2] = in_l + 2*IN_E;  sa.n4[2] = IN_E / 4;
    sa.src[3] = Wq;    sa.dh[3] = W_h;            sa.dl[3] = W_l;            sa.n4[3] = W_E / 4;
    sa.src[4] = Wke;   sa.dh[4] = W_h + W_E;      sa.dl[4] = W_l + W_E;      sa.n4[4] = W_E / 4;
    sa.src[5] = Wv;    sa.dh[5] = W_h + 2*W_E;    sa.dl[5] = W_l + 2*W_E;    sa.n4[5] = W_E / 4;
    sa.src[6] = Wkr;   sa.dh[6] = W_h + 3*W_E;    sa.dl[6] = W_l + 3*W_E;    sa.n4[6] = W_E / 4;
    sa.src[7] = Wf;    sa.dh[7] = W_h + 4*W_E;    sa.dl[7] = W_l + 4*W_E;    sa.n4[7] = W_E / 4;
    split_all<<<dim3(2048, 8), blk, 0, stream>>>(sa);
    posenc_split<<<dim3(IN_E / 256), blk, 0, stream>>>(in_h + 3*(i64)IN_E, in_l + 3*(i64)IN_E);

    {
        TNArgs p = {};
        p.Ah = in_h; p.Al = in_l; p.Bh = W_h; p.Bl = W_l;
        p.sAz = IN_E; p.sBz = W_E;
        p.O1h = P_h; p.O1l = P_l; p.O2h = qv_h; p.O2l = qv_l;
        p.b1 = u_p; p.b2 = v_p;
        p.K = DMODEL; p.mode = 1;
        mfma_tn128<<<dim3(DMODEL / 128, SEQ / 128, 4), blk, 0, stream>>>(p);
    }

    transpose_vv<<<dim3(SEQ / 64, NHEADS), blk, 0, stream>>>(
        P_h + 2*(i64)IN_E, P_l + 2*(i64)IN_E, vvT_h, vvT_l);

    {
        TNArgs p = {};
        p.Ah = P_h; p.Al = P_l;
        p.Bh = P_h + IN_E; p.Bl = P_l + IN_E;
        p.sAz = HEAD_E; p.sBz = HEAD_E;
        p.Cf = weights; p.sCz = (i64)SEQ * SEQ; p.ldc = SEQ;
        p.K = DHEAD; p.mode = 0;
        mfma_tn128<<<dim3(SEQ / 128, SEQ / 128, NHEADS), blk, 0, stream>>>(p);
    }

    for (int h0 = 0; h0 < NHEADS; h0 += chunk) {
        const int ch = (h0 + chunk <= NHEADS) ? chunk : (NHEADS - h0);
        TNArgs p = {};
        p.Ah = qv_h + (i64)h0 * HEAD_E; p.Al = qv_l + (i64)h0 * HEAD_E;
        p.Bh = P_h + 3*(i64)IN_E + (i64)h0 * HEAD_E;
        p.Bl = P_l + 3*(i64)IN_E + (i64)h0 * HEAD_E;
        p.sAz = HEAD_E; p.sBz = HEAD_E;
        p.Cf = G; p.sCz = (i64)SEQ * SEQ; p.ldc = SEQ;
        p.K = DHEAD; p.mode = 0;
        mfma_tn128<<<dim3(SEQ / 128, SEQ / 128, ch), blk, 0, stream>>>(p);
        softmax_rows<<<dim3(SEQ, ch), blk, 0, stream>>>(weights, G, mask, lmin, h0);
    }

    mfma_pv<<<dim3(1, SEQ / 64, NHEADS), blk, 0, stream>>>(weights, vvT_h, vvT_l, o_h, o_l);

    {
        TNArgs p = {};
        p.Ah = o_h; p.Al = o_l;
        p.Bh = W_h + 4*(i64)W_E; p.Bl = W_l + 4*(i64)W_E;
        p.sAz = 0; p.sBz = 0;
        p.Cf = out_final; p.sCz = 0; p.ldc = DMODEL;
        p.K = DMODEL; p.mode = 2;
        mfma_tn128<<<dim3(DMODEL / 128, SEQ / 128, 1), blk, 0, stream>>>(p);
    }

    loss_kernel<<<dim3(1), dim3(1024), 0, stream>>>(lmin, loss);
}